// Round 1
// baseline (2708.730 us; speedup 1.0000x reference)
//
#include <hip/hip_runtime.h>
#include <hip/hip_bf16.h>
#include <math.h>

// Problem constants (from reference): B=4, T=2048, E=1024, H=16, D=64.
#define B_  4
#define T_  2048
#define E_  1024
#define H_  16
#define D_  64
#define HD_ 1024
#define M_  (B_*T_)   // 8192 rows in all GEMMs

// Workspace layout (floats): Pq | Pk | Pv | Ao, each M_*HD_ = 8388608 floats
// (33.55 MB). Total 134.2 MB.
//
// Raw-reshape equivalence: qh[b,h,t,d] = Pq[(b*H+h)*T*D + t*D + d]  (contiguous
// (T,D) row-major per head) because (B,T,H*D).reshape(B,H,T,D) is a flat view.

// ---------------------------------------------------------------------------
// GEMM: C[M x N] = A[M x K] @ W[K x N] + bias[N], all row-major fp32.
// 128x128 block tile, BK=16, 256 threads, 8x8 per thread.
// ---------------------------------------------------------------------------
#define BM 128
#define BN 128
#define BK 16

__global__ __launch_bounds__(256) void gemm_bias(
    const float* __restrict__ A, const float* __restrict__ W,
    const float* __restrict__ bias, float* __restrict__ C,
    int Mdim, int Ndim, int Kdim)
{
  __shared__ float As[BK][BM];   // A tile stored transposed: As[k][m]
  __shared__ float Bs[BK][BN];   // Bs[k][n]

  const int tid = threadIdx.x;
  const int bx = blockIdx.x;     // N tile index
  const int by = blockIdx.y;     // M tile index
  const int tx = tid & 15;       // 0..15 -> output cols tx*8..+7
  const int ty = tid >> 4;       // 0..15 -> output rows ty*8..+7

  float acc[8][8];
#pragma unroll
  for (int i = 0; i < 8; ++i)
#pragma unroll
    for (int j = 0; j < 8; ++j) acc[i][j] = 0.f;

  // Global staging indices.
  const int arow = tid >> 2;     // 0..63  (A tile row; +64 for second half)
  const int ak4  = tid & 3;      // 0..3   (A tile float4 column)
  const int brow = tid >> 5;     // 0..7   (W tile row; +8 for second half)
  const int bn4  = tid & 31;     // 0..31  (W tile float4 column)

  const float* Ag  = A + (size_t)(by * BM + arow) * Kdim + ak4 * 4;
  const float* Ag2 = Ag + (size_t)64 * Kdim;
  const float* Wg  = W + (size_t)brow * Ndim + bx * BN + bn4 * 4;
  const float* Wg2 = Wg + (size_t)8 * Ndim;

  for (int k0 = 0; k0 < Kdim; k0 += BK) {
    const float4 a0 = *(const float4*)(Ag  + k0);
    const float4 a1 = *(const float4*)(Ag2 + k0);
    const float4 b0 = *(const float4*)(Wg  + (size_t)k0 * Ndim);
    const float4 b1 = *(const float4*)(Wg2 + (size_t)k0 * Ndim);
    __syncthreads();               // previous tile fully consumed
    As[ak4*4+0][arow] = a0.x;
    As[ak4*4+1][arow] = a0.y;
    As[ak4*4+2][arow] = a0.z;
    As[ak4*4+3][arow] = a0.w;
    As[ak4*4+0][64+arow] = a1.x;
    As[ak4*4+1][64+arow] = a1.y;
    As[ak4*4+2][64+arow] = a1.z;
    As[ak4*4+3][64+arow] = a1.w;
    *(float4*)&Bs[brow][bn4*4]   = b0;
    *(float4*)&Bs[brow+8][bn4*4] = b1;
    __syncthreads();
#pragma unroll
    for (int k = 0; k < BK; ++k) {
      float a[8], b[8];
      *(float4*)&a[0] = *(const float4*)&As[k][ty*8];
      *(float4*)&a[4] = *(const float4*)&As[k][ty*8+4];
      *(float4*)&b[0] = *(const float4*)&Bs[k][tx*8];
      *(float4*)&b[4] = *(const float4*)&Bs[k][tx*8+4];
#pragma unroll
      for (int i = 0; i < 8; ++i)
#pragma unroll
        for (int j = 0; j < 8; ++j)
          acc[i][j] = fmaf(a[i], b[j], acc[i][j]);
    }
  }

  const int row0 = by * BM + ty * 8;
  const int col0 = bx * BN + tx * 8;
  float bv[8];
#pragma unroll
  for (int j = 0; j < 8; ++j) bv[j] = bias[col0 + j];
#pragma unroll
  for (int i = 0; i < 8; ++i) {
    float4 o0, o1;
    o0.x = acc[i][0] + bv[0]; o0.y = acc[i][1] + bv[1];
    o0.z = acc[i][2] + bv[2]; o0.w = acc[i][3] + bv[3];
    o1.x = acc[i][4] + bv[4]; o1.y = acc[i][5] + bv[5];
    o1.z = acc[i][6] + bv[6]; o1.w = acc[i][7] + bv[7];
    *(float4*)(C + (size_t)(row0 + i) * Ndim + col0)     = o0;
    *(float4*)(C + (size_t)(row0 + i) * Ndim + col0 + 4) = o1;
  }
}

// ---------------------------------------------------------------------------
// Fused causal attention (flash-style, fp32). One block = one (b,h,Q-tile).
// 256 threads: thread (rg,cg) = (tid>>4, tid&15) owns the 4x4 S/O patch at
// rows rg*4.., cols cg*4.. ; softmax row stats reduced across the 16 cg lanes.
// LDS float4 index swizzle c4 ^= (row>>2)&7 kills the stride-64 K-row bank
// conflict (would be 16-way otherwise).
// ---------------------------------------------------------------------------
#define QT 64
#define KT 64

__device__ __forceinline__ float4& sw4(float* base, int row, int c4) {
  return *(float4*)(base + 4 * ((row << 4) | (c4 ^ ((row >> 2) & 7))));
}

__global__ __launch_bounds__(256) void attn_fused(
    const float* __restrict__ Pq, const float* __restrict__ Pk,
    const float* __restrict__ Pv, float* __restrict__ Ao)
{
  __shared__ float Qs[QT * D_];
  __shared__ float Ks[KT * D_];
  __shared__ float Vs[KT * D_];
  __shared__ float Ps[QT * KT];

  const int tid = threadIdx.x;
  const int qt = blockIdx.x, h = blockIdx.y, b = blockIdx.z;
  const size_t headoff = (size_t)(b * H_ + h) * T_ * D_;
  const float* Q = Pq + headoff + (size_t)qt * QT * D_;
  const float* K = Pk + headoff;
  const float* V = Pv + headoff;

  const int rg = tid >> 4;   // 0..15: rows rg*4..rg*4+3
  const int cg = tid & 15;   // 0..15: cols cg*4..cg*4+3

  // Stage Q tile (4096 floats = 1024 float4, contiguous source).
#pragma unroll
  for (int i = 0; i < 4; ++i) {
    const int f = tid + i * 256;
    sw4(Qs, f >> 4, f & 15) = *(const float4*)(Q + f * 4);
  }

  float O[4][4];
  float m[4], l[4];
#pragma unroll
  for (int i = 0; i < 4; ++i) {
    m[i] = -INFINITY; l[i] = 0.f;
#pragma unroll
    for (int j = 0; j < 4; ++j) O[i][j] = 0.f;
  }

  const float scale = 0.03125f;  // 1/sqrt(E) = 1/32

  for (int kt = 0; kt <= qt; ++kt) {
    __syncthreads();   // previous K/V/P fully consumed (also covers Q staging)
#pragma unroll
    for (int i = 0; i < 4; ++i) {
      const int f = tid + i * 256;
      const int row = f >> 4, c4 = f & 15;
      sw4(Ks, row, c4) = *(const float4*)(K + (size_t)kt * KT * D_ + f * 4);
      sw4(Vs, row, c4) = *(const float4*)(V + (size_t)kt * KT * D_ + f * 4);
    }
    __syncthreads();

    // ---- S = (Q K^T) * scale, 4x4 patch per thread ----
    float s[4][4];
#pragma unroll
    for (int i = 0; i < 4; ++i)
#pragma unroll
      for (int j = 0; j < 4; ++j) s[i][j] = 0.f;
#pragma unroll
    for (int k4 = 0; k4 < 16; ++k4) {
      float4 qv[4], kv[4];
#pragma unroll
      for (int i = 0; i < 4; ++i) qv[i] = sw4(Qs, rg * 4 + i, k4);
#pragma unroll
      for (int j = 0; j < 4; ++j) kv[j] = sw4(Ks, cg * 4 + j, k4);
#pragma unroll
      for (int i = 0; i < 4; ++i)
#pragma unroll
        for (int j = 0; j < 4; ++j)
          s[i][j] += qv[i].x * kv[j].x + qv[i].y * kv[j].y +
                     qv[i].z * kv[j].z + qv[i].w * kv[j].w;
    }
#pragma unroll
    for (int i = 0; i < 4; ++i)
#pragma unroll
      for (int j = 0; j < 4; ++j) s[i][j] *= scale;
    if (kt == qt) {   // diagonal tile: causal mask (s0 == t0)
#pragma unroll
      for (int i = 0; i < 4; ++i)
#pragma unroll
        for (int j = 0; j < 4; ++j)
          if (cg * 4 + j > rg * 4 + i) s[i][j] = -INFINITY;
    }

    // ---- online softmax ----
    float rmax[4];
#pragma unroll
    for (int i = 0; i < 4; ++i)
      rmax[i] = fmaxf(fmaxf(s[i][0], s[i][1]), fmaxf(s[i][2], s[i][3]));
#pragma unroll
    for (int x = 1; x < 16; x <<= 1)
#pragma unroll
      for (int i = 0; i < 4; ++i)
        rmax[i] = fmaxf(rmax[i], __shfl_xor(rmax[i], x, 64));

    float alpha[4], p[4][4], rsum[4];
#pragma unroll
    for (int i = 0; i < 4; ++i) {
      const float mn = fmaxf(m[i], rmax[i]);
      alpha[i] = expf(m[i] - mn);       // exp(-inf)=0 on first tile
      m[i] = mn;
      rsum[i] = 0.f;
#pragma unroll
      for (int j = 0; j < 4; ++j) {
        p[i][j] = expf(s[i][j] - mn);   // masked (-inf) -> 0
        rsum[i] += p[i][j];
      }
    }
#pragma unroll
    for (int x = 1; x < 16; x <<= 1)
#pragma unroll
      for (int i = 0; i < 4; ++i)
        rsum[i] += __shfl_xor(rsum[i], x, 64);
#pragma unroll
    for (int i = 0; i < 4; ++i) {
      l[i] = l[i] * alpha[i] + rsum[i];
#pragma unroll
      for (int j = 0; j < 4; ++j) O[i][j] *= alpha[i];
    }

    // ---- stage P, then O += P V ----
#pragma unroll
    for (int i = 0; i < 4; ++i) {
      float4 pw; pw.x = p[i][0]; pw.y = p[i][1]; pw.z = p[i][2]; pw.w = p[i][3];
      sw4(Ps, rg * 4 + i, cg) = pw;
    }
    __syncthreads();
#pragma unroll
    for (int j4 = 0; j4 < 16; ++j4) {
      float4 pv[4], vv[4];
#pragma unroll
      for (int i = 0; i < 4; ++i)  pv[i] = sw4(Ps, rg * 4 + i, j4);
#pragma unroll
      for (int jj = 0; jj < 4; ++jj) vv[jj] = sw4(Vs, j4 * 4 + jj, cg);
#pragma unroll
      for (int i = 0; i < 4; ++i) {
        O[i][0] += pv[i].x * vv[0].x + pv[i].y * vv[1].x +
                   pv[i].z * vv[2].x + pv[i].w * vv[3].x;
        O[i][1] += pv[i].x * vv[0].y + pv[i].y * vv[1].y +
                   pv[i].z * vv[2].y + pv[i].w * vv[3].y;
        O[i][2] += pv[i].x * vv[0].z + pv[i].y * vv[1].z +
                   pv[i].z * vv[2].z + pv[i].w * vv[3].z;
        O[i][3] += pv[i].x * vv[0].w + pv[i].y * vv[1].w +
                   pv[i].z * vv[2].w + pv[i].w * vv[3].w;
      }
    }
  }

  // ---- epilogue: O/l, write to (B,T,H*D) layout ----
  const int t0 = qt * QT;
#pragma unroll
  for (int i = 0; i < 4; ++i) {
    const float inv = 1.f / l[i];
    float4 o;
    o.x = O[i][0] * inv; o.y = O[i][1] * inv;
    o.z = O[i][2] * inv; o.w = O[i][3] * inv;
    *(float4*)(Ao + (size_t)(b * T_ + t0 + rg * 4 + i) * HD_ + h * D_ + cg * 4) = o;
  }
}

// ---------------------------------------------------------------------------
extern "C" void kernel_launch(void* const* d_in, const int* in_sizes, int n_in,
                              void* d_out, int out_size, void* d_ws, size_t ws_size,
                              hipStream_t stream) {
  const float* q  = (const float*)d_in[0];
  const float* k  = (const float*)d_in[1];
  const float* v  = (const float*)d_in[2];
  const float* Wq = (const float*)d_in[3];
  const float* bq = (const float*)d_in[4];
  const float* Wk = (const float*)d_in[5];
  const float* bk = (const float*)d_in[6];
  const float* Wv = (const float*)d_in[7];
  const float* bv = (const float*)d_in[8];
  const float* Wo = (const float*)d_in[9];
  const float* bo = (const float*)d_in[10];
  float* out = (float*)d_out;

  float* ws = (float*)d_ws;
  const size_t PSZ = (size_t)M_ * HD_;  // 8388608 floats
  float* Pq = ws;
  float* Pk = ws + PSZ;
  float* Pv = ws + 2 * PSZ;
  float* Ao = ws + 3 * PSZ;

  dim3 gg(HD_ / BN, M_ / BM);  // (8, 64)
  gemm_bias<<<gg, 256, 0, stream>>>(q, Wq, bq, Pq, M_, HD_, E_);
  gemm_bias<<<gg, 256, 0, stream>>>(k, Wk, bk, Pk, M_, HD_, E_);
  gemm_bias<<<gg, 256, 0, stream>>>(v, Wv, bv, Pv, M_, HD_, E_);

  attn_fused<<<dim3(T_ / QT, H_, B_), 256, 0, stream>>>(Pq, Pk, Pv, Ao);

  gemm_bias<<<gg, 256, 0, stream>>>(Ao, Wo, bo, out, M_, E_, HD_);
}

// Round 2
// 521.247 us; speedup vs baseline: 5.1966x; 5.1966x over previous
//
#include <hip/hip_runtime.h>
#include <hip/hip_bf16.h>
#include <math.h>

// B=4, T=2048, E=1024, H=16, D=64. All GEMMs are 8192x1024x1024.
// Head slice equivalence (validated round 1): head hd=b*16+h of any projection
// is the contiguous (2048 x 64) bf16 row-major block at offset hd*131072 elems.

typedef unsigned short ushort_t;
typedef __attribute__((ext_vector_type(8))) short s8v;      // 8 bf16 = 4 VGPR
typedef __attribute__((ext_vector_type(8))) unsigned short us8;
typedef __attribute__((ext_vector_type(4))) float f4v;

__device__ __forceinline__ unsigned short f2bf(float x) {
  __hip_bfloat16 h = __float2bfloat16(x);
  unsigned short u; __builtin_memcpy(&u, &h, 2); return u;
}

__device__ __forceinline__ void gload16(const void* g, void* l) {
  __builtin_amdgcn_global_load_lds(
      (const __attribute__((address_space(1))) unsigned int*)g,
      (__attribute__((address_space(3))) unsigned int*)l, 16, 0, 0);
}

// ---------------------------------------------------------------- cast f32->bf16
__global__ __launch_bounds__(256) void castk(const float* __restrict__ src,
                                             ushort_t* __restrict__ dst, int n8) {
  int i = blockIdx.x * 256 + threadIdx.x;
  if (i >= n8) return;
  const float4* s4 = (const float4*)src + (size_t)i * 2;
  float4 a = s4[0], b = s4[1];
  us8 o;
  o[0]=f2bf(a.x); o[1]=f2bf(a.y); o[2]=f2bf(a.z); o[3]=f2bf(a.w);
  o[4]=f2bf(b.x); o[5]=f2bf(b.y); o[6]=f2bf(b.z); o[7]=f2bf(b.w);
  *(us8*)(dst + (size_t)i * 8) = o;
}

// ------------------------------------------- W (1024x1024 f32) -> W^T (N,K) bf16
__global__ __launch_bounds__(256) void wtrans(const float* __restrict__ W,
                                              ushort_t* __restrict__ Wt) {
  __shared__ unsigned tr[64][65];
  const int k0 = blockIdx.y * 64, n0 = blockIdx.x * 64;
  const int tid = threadIdx.x;
  {
    const int rr = tid >> 4, c4 = tid & 15;
#pragma unroll
    for (int p = 0; p < 4; ++p) {
      const int k = p * 16 + rr;
      float4 v = *(const float4*)(W + (size_t)(k0 + k) * 1024 + n0 + c4 * 4);
      tr[c4*4+0][k] = f2bf(v.x); tr[c4*4+1][k] = f2bf(v.y);
      tr[c4*4+2][k] = f2bf(v.z); tr[c4*4+3][k] = f2bf(v.w);
    }
  }
  __syncthreads();
  const int r = tid >> 3, s = tid & 7;
#pragma unroll
  for (int p = 0; p < 2; ++p) {
    const int n = p * 32 + r;
    us8 o;
#pragma unroll
    for (int j = 0; j < 8; ++j) o[j] = (ushort_t)tr[n][s*8+j];
    *(us8*)(Wt + (size_t)(n0 + n) * 1024 + k0 + s * 8) = o;
  }
}

// -------------------- per-head (2048x64) bf16 -> (64x2048) bf16  (V transpose)
__global__ __launch_bounds__(256) void vtrans(const ushort_t* __restrict__ Pv,
                                              ushort_t* __restrict__ Pvt) {
  __shared__ unsigned tr[64][65];
  const int t0 = blockIdx.x * 64, hd = blockIdx.y;
  const ushort_t* src = Pv + (size_t)hd * 131072;
  ushort_t* dst = Pvt + (size_t)hd * 131072;
  const int tid = threadIdx.x;
  const int r = tid >> 3, s = tid & 7;
#pragma unroll
  for (int p = 0; p < 2; ++p) {
    const int t = p * 32 + r;
    us8 v = *(const us8*)(src + (size_t)(t0 + t) * 64 + s * 8);
#pragma unroll
    for (int j = 0; j < 8; ++j) tr[s*8+j][t] = v[j];
  }
  __syncthreads();
#pragma unroll
  for (int p = 0; p < 2; ++p) {
    const int d = p * 32 + r;
    us8 o;
#pragma unroll
    for (int j = 0; j < 8; ++j) o[j] = (ushort_t)tr[d][s*8+j];
    *(us8*)(dst + (size_t)d * 2048 + t0 + s * 8) = o;
  }
}

// ----------------------------------------------------------------- bf16 GEMM
// C[M,N] = A[M,K] @ Bt[N,K]^T + bias. 128x128 tile, BK=64, 4 waves of 64x64.
// LDS rows 128B, slot8 XOR (row&7) swizzle (conflict-free b128 frag reads);
// global_load_lds stages with inverse-swizzled per-lane SOURCE (linear dest).
template<int OUTF32>
__global__ __launch_bounds__(256) void gemm_bf16(
    const ushort_t* __restrict__ A, const ushort_t* __restrict__ Bt,
    const float* __restrict__ bias, void* __restrict__ Cout,
    int Mdim, int Ndim, int Kdim)
{
  __shared__ __align__(16) ushort_t As[128 * 64];
  __shared__ __align__(16) ushort_t Bs[128 * 64];
  const int tid = threadIdx.x;
  const int m0 = blockIdx.y * 128, n0 = blockIdx.x * 128;
  const int w = tid >> 6, lane = tid & 63, lo = lane & 15, hi = lane >> 4;
  const int wm = (w >> 1) * 64, wn = (w & 1) * 64;
  const int srow = tid >> 3, sslot = tid & 7;

  f4v acc[4][4];
#pragma unroll
  for (int i = 0; i < 4; ++i)
#pragma unroll
    for (int j = 0; j < 4; ++j) { f4v z = {0.f,0.f,0.f,0.f}; acc[i][j] = z; }

  for (int k0 = 0; k0 < Kdim; k0 += 64) {
#pragma unroll
    for (int i = 0; i < 4; ++i) {
      const int row = i * 32 + srow;
      const int sw = (sslot ^ (row & 7)) * 8;
      gload16(A  + (size_t)(m0 + row) * Kdim + k0 + sw, &As[(i * 256 + tid) * 8]);
      gload16(Bt + (size_t)(n0 + row) * Kdim + k0 + sw, &Bs[(i * 256 + tid) * 8]);
    }
    __syncthreads();
#pragma unroll
    for (int ks = 0; ks < 2; ++ks) {
      const int slot = ks * 4 + hi;
      s8v av[4], bv[4];
#pragma unroll
      for (int i = 0; i < 4; ++i) {
        const int ra = wm + i * 16 + lo;
        av[i] = *(const s8v*)&As[ra * 64 + ((slot ^ (ra & 7)) << 3)];
        const int rb = wn + i * 16 + lo;
        bv[i] = *(const s8v*)&Bs[rb * 64 + ((slot ^ (rb & 7)) << 3)];
      }
#pragma unroll
      for (int am = 0; am < 4; ++am)
#pragma unroll
        for (int an = 0; an < 4; ++an)
          acc[am][an] = __builtin_amdgcn_mfma_f32_16x16x32_bf16(
              av[am], bv[an], acc[am][an], 0, 0, 0);
    }
    __syncthreads();
  }

#pragma unroll
  for (int an = 0; an < 4; ++an) {
    const int n = n0 + wn + an * 16 + lo;
    const float bsv = bias[n];
#pragma unroll
    for (int am = 0; am < 4; ++am) {
      const int mb = m0 + wm + am * 16 + hi * 4;
#pragma unroll
      for (int r = 0; r < 4; ++r) {
        const float v = acc[am][an][r] + bsv;
        if (OUTF32) ((float*)Cout)[(size_t)(mb + r) * Ndim + n] = v;
        else ((ushort_t*)Cout)[(size_t)(mb + r) * Ndim + n] = f2bf(v);
      }
    }
  }
}

// -------------------------------------------------------- fused causal attention
// Block = (qt, head): 4 waves, wave w owns q-rows [16w,16w+16) of a 64-row tile.
// Q frags in regs (global). K, V^T staged via swizzled-source global_load_lds.
// Online softmax in regs (shfl over 16-lane col groups); P re-fragmented via
// wave-private swizzled fp32 LDS (2-way banks = free).
__global__ __launch_bounds__(256) void attn_mfma(
    const ushort_t* __restrict__ Pq, const ushort_t* __restrict__ Pk,
    const ushort_t* __restrict__ Pvt, ushort_t* __restrict__ Ao)
{
  __shared__ __align__(16) ushort_t Ks[64 * 64];
  __shared__ __align__(16) ushort_t Vts[64 * 64];
  __shared__ __align__(16) float Ps[64 * 64];

  const int tid = threadIdx.x;
  const int qt = blockIdx.x, hd = blockIdx.y;
  const int b = hd >> 4, h = hd & 15;
  const int w = tid >> 6, lane = tid & 63, lo = lane & 15, hi = lane >> 4;
  const ushort_t* Qh = Pq + (size_t)hd * 131072;
  const ushort_t* Kh = Pk + (size_t)hd * 131072;
  const ushort_t* Vh = Pvt + (size_t)hd * 131072;

  s8v qa[2];
#pragma unroll
  for (int ks = 0; ks < 2; ++ks)
    qa[ks] = *(const s8v*)(Qh + (size_t)(qt * 64 + w * 16 + lo) * 64 + ks * 32 + hi * 8);

  f4v od[4];
#pragma unroll
  for (int f = 0; f < 4; ++f) { f4v z = {0.f,0.f,0.f,0.f}; od[f] = z; }
  float m[4], l[4];
#pragma unroll
  for (int r = 0; r < 4; ++r) { m[r] = -INFINITY; l[r] = 0.f; }

  const int srow = tid >> 3, sslot = tid & 7;

  for (int kt = 0; kt <= qt; ++kt) {
#pragma unroll
    for (int i = 0; i < 2; ++i) {
      const int row = i * 32 + srow;
      const int sw = (sslot ^ (row & 7)) * 8;
      gload16(Kh + (size_t)(kt * 64 + row) * 64 + sw, &Ks[(i * 256 + tid) * 8]);
      gload16(Vh + (size_t)row * 2048 + kt * 64 + sw, &Vts[(i * 256 + tid) * 8]);
    }
    __syncthreads();

    // ---- S = Q K^T (C-layout: lane holds S[4hi+r][16f+lo]) ----
    f4v sf[4];
#pragma unroll
    for (int f = 0; f < 4; ++f) { f4v z = {0.f,0.f,0.f,0.f}; sf[f] = z; }
#pragma unroll
    for (int ks = 0; ks < 2; ++ks) {
      const int slot = ks * 4 + hi;
      s8v kb[4];
#pragma unroll
      for (int f = 0; f < 4; ++f) {
        const int rk = f * 16 + lo;
        kb[f] = *(const s8v*)&Ks[rk * 64 + ((slot ^ (rk & 7)) << 3)];
      }
#pragma unroll
      for (int f = 0; f < 4; ++f)
        sf[f] = __builtin_amdgcn_mfma_f32_16x16x32_bf16(qa[ks], kb[f], sf[f], 0, 0, 0);
    }

    // ---- online softmax ----
    float sc[4][4];
#pragma unroll
    for (int f = 0; f < 4; ++f)
#pragma unroll
      for (int r = 0; r < 4; ++r) sc[r][f] = sf[f][r] * 0.03125f;
    if (kt == qt) {
#pragma unroll
      for (int r = 0; r < 4; ++r)
#pragma unroll
        for (int f = 0; f < 4; ++f)
          if (16 * f + lo > 16 * w + 4 * hi + r) sc[r][f] = -INFINITY;
    }
    float rmax[4], al[4], rs[4];
#pragma unroll
    for (int r = 0; r < 4; ++r)
      rmax[r] = fmaxf(fmaxf(sc[r][0], sc[r][1]), fmaxf(sc[r][2], sc[r][3]));
#pragma unroll
    for (int x = 1; x < 16; x <<= 1)
#pragma unroll
      for (int r = 0; r < 4; ++r) rmax[r] = fmaxf(rmax[r], __shfl_xor(rmax[r], x, 64));
#pragma unroll
    for (int r = 0; r < 4; ++r) {
      const float mn = fmaxf(m[r], rmax[r]);
      al[r] = __expf(m[r] - mn);
      m[r] = mn; rs[r] = 0.f;
    }
#pragma unroll
    for (int r = 0; r < 4; ++r)
#pragma unroll
      for (int f = 0; f < 4; ++f) {
        const float p = __expf(sc[r][f] - m[r]);
        sc[r][f] = p; rs[r] += p;
      }
#pragma unroll
    for (int x = 1; x < 16; x <<= 1)
#pragma unroll
      for (int r = 0; r < 4; ++r) rs[r] += __shfl_xor(rs[r], x, 64);
#pragma unroll
    for (int r = 0; r < 4; ++r) l[r] = l[r] * al[r] + rs[r];
#pragma unroll
    for (int f = 0; f < 4; ++f)
#pragma unroll
      for (int r = 0; r < 4; ++r) od[f][r] *= al[r];

    // ---- stage P (wave-private rows, fp32, slot16^(t&15) swizzle) ----
#pragma unroll
    for (int r = 0; r < 4; ++r) {
      const int t = 16 * w + 4 * hi + r;
#pragma unroll
      for (int f = 0; f < 4; ++f) {
        const int s = 16 * f + lo;
        Ps[t * 64 + (((s >> 2) ^ (t & 15)) << 2) + (s & 3)] = sc[r][f];
      }
    }

    // ---- O += P V ----
#pragma unroll
    for (int ks = 0; ks < 2; ++ks) {
      const int t = 16 * w + lo;
      const int s0 = (ks * 8 + hi * 2) ^ (t & 15);
      const int s1 = (ks * 8 + hi * 2 + 1) ^ (t & 15);
      f4v p0 = *(const f4v*)&Ps[t * 64 + s0 * 4];
      f4v p1 = *(const f4v*)&Ps[t * 64 + s1 * 4];
      s8v pa;
#pragma unroll
      for (int j = 0; j < 4; ++j) {
        pa[j]     = (short)f2bf(p0[j]);
        pa[4 + j] = (short)f2bf(p1[j]);
      }
      const int slot = ks * 4 + hi;
      s8v vb[4];
#pragma unroll
      for (int f = 0; f < 4; ++f) {
        const int rd = f * 16 + lo;
        vb[f] = *(const s8v*)&Vts[rd * 64 + ((slot ^ (rd & 7)) << 3)];
      }
#pragma unroll
      for (int f = 0; f < 4; ++f)
        od[f] = __builtin_amdgcn_mfma_f32_16x16x32_bf16(pa, vb[f], od[f], 0, 0, 0);
    }
    __syncthreads();
  }

  // ---- epilogue ----
  float inv[4];
#pragma unroll
  for (int r = 0; r < 4; ++r) inv[r] = 1.0f / l[r];
#pragma unroll
  for (int f = 0; f < 4; ++f)
#pragma unroll
    for (int r = 0; r < 4; ++r) {
      const int t = qt * 64 + 16 * w + 4 * hi + r;
      const int d = 16 * f + lo;
      Ao[(size_t)(b * 2048 + t) * 1024 + h * 64 + d] = f2bf(od[f][r] * inv[r]);
    }
}

// ---------------------------------------------------------------------------
extern "C" void kernel_launch(void* const* d_in, const int* in_sizes, int n_in,
                              void* d_out, int out_size, void* d_ws, size_t ws_size,
                              hipStream_t stream) {
  const float* q  = (const float*)d_in[0];
  const float* k  = (const float*)d_in[1];
  const float* v  = (const float*)d_in[2];
  const float* Wq = (const float*)d_in[3];
  const float* bq = (const float*)d_in[4];
  const float* Wk = (const float*)d_in[5];
  const float* bk = (const float*)d_in[6];
  const float* Wv = (const float*)d_in[7];
  const float* bv = (const float*)d_in[8];
  const float* Wo = (const float*)d_in[9];
  const float* bo = (const float*)d_in[10];
  float* out = (float*)d_out;

  char* wsb = (char*)d_ws;
  ushort_t* qb  = (ushort_t*)(wsb + 0);          // 16 MB each
  ushort_t* kb  = (ushort_t*)(wsb + 16777216);
  ushort_t* vb  = (ushort_t*)(wsb + 33554432);
  ushort_t* Wqt = (ushort_t*)(wsb + 50331648);   // 2 MB each
  ushort_t* Wkt = (ushort_t*)(wsb + 52428800);
  ushort_t* Wvt = (ushort_t*)(wsb + 54525952);
  ushort_t* Wot = (ushort_t*)(wsb + 56623104);
  ushort_t* Pq  = (ushort_t*)(wsb + 58720256);
  ushort_t* Pk  = (ushort_t*)(wsb + 75497472);
  ushort_t* Pv  = (ushort_t*)(wsb + 92274688);   // end = 109,051,904 B
  ushort_t* Pvt = qb;   // qb dead after Q-projection
  ushort_t* Ao  = kb;   // kb dead after K-projection

  castk<<<4096, 256, 0, stream>>>(q, qb, 1048576);
  castk<<<4096, 256, 0, stream>>>(k, kb, 1048576);
  castk<<<4096, 256, 0, stream>>>(v, vb, 1048576);
  wtrans<<<dim3(16, 16), 256, 0, stream>>>(Wq, Wqt);
  wtrans<<<dim3(16, 16), 256, 0, stream>>>(Wk, Wkt);
  wtrans<<<dim3(16, 16), 256, 0, stream>>>(Wv, Wvt);
  wtrans<<<dim3(16, 16), 256, 0, stream>>>(Wo, Wot);

  gemm_bf16<0><<<dim3(8, 64), 256, 0, stream>>>(qb, Wqt, bq, Pq, 8192, 1024, 1024);
  gemm_bf16<0><<<dim3(8, 64), 256, 0, stream>>>(kb, Wkt, bk, Pk, 8192, 1024, 1024);
  gemm_bf16<0><<<dim3(8, 64), 256, 0, stream>>>(vb, Wvt, bv, Pv, 8192, 1024, 1024);

  vtrans<<<dim3(32, 64), 256, 0, stream>>>(Pv, Pvt);
  attn_mfma<<<dim3(32, 64), 256, 0, stream>>>(Pq, Pk, Pvt, Ao);

  gemm_bf16<1><<<dim3(8, 64), 256, 0, stream>>>(Ao, Wot, bo, out, 8192, 1024, 1024);
}

// Round 3
// 367.884 us; speedup vs baseline: 7.3630x; 1.4169x over previous
//
#include <hip/hip_runtime.h>
#include <hip/hip_bf16.h>
#include <math.h>

// B=4, T=2048, E=1024, H=16, D=64. All GEMMs are 8192x1024x1024.
// Head hd=b*16+h of any projection = contiguous (2048x64) row-major block at
// offset hd*131072 elems (raw-reshape equivalence, validated round 1).

typedef unsigned short ushort_t;
typedef __attribute__((ext_vector_type(8))) short s8v;      // 8 bf16 = 4 VGPR
typedef __attribute__((ext_vector_type(8))) unsigned short us8;
typedef __attribute__((ext_vector_type(4))) float f4v;

#define BAR()    __builtin_amdgcn_s_barrier()
#define LFENCE() asm volatile("" ::: "memory")
#define VMCNT(n) asm volatile("s_waitcnt vmcnt(" #n ")" ::: "memory")

__device__ __forceinline__ unsigned short f2bf(float x) {
  __hip_bfloat16 h = __float2bfloat16(x);
  unsigned short u; __builtin_memcpy(&u, &h, 2); return u;
}

__device__ __forceinline__ void gload16(const void* g, void* l) {
  __builtin_amdgcn_global_load_lds(
      (const __attribute__((address_space(1))) unsigned int*)g,
      (__attribute__((address_space(3))) unsigned int*)l, 16, 0, 0);
}

// -------------------------------------------- cast f32->bf16 (q,k,v in one)
__global__ __launch_bounds__(256) void castk3(const float* __restrict__ q,
                                              const float* __restrict__ k,
                                              const float* __restrict__ v,
                                              ushort_t* __restrict__ dst) {
  const int y = blockIdx.y;
  const float* src = (y == 0) ? q : (y == 1) ? k : v;
  ushort_t* d = dst + (size_t)y * 8388608;
  int i = blockIdx.x * 256 + threadIdx.x;   // 0..1048575 (x8 elems)
  const float4* s4 = (const float4*)src + (size_t)i * 2;
  float4 a = s4[0], b = s4[1];
  us8 o;
  o[0]=f2bf(a.x); o[1]=f2bf(a.y); o[2]=f2bf(a.z); o[3]=f2bf(a.w);
  o[4]=f2bf(b.x); o[5]=f2bf(b.y); o[6]=f2bf(b.z); o[7]=f2bf(b.w);
  *(us8*)(d + (size_t)i * 8) = o;
}

// ---------------------------- W (1024x1024 f32) -> W^T (N,K) bf16, 4 weights
__global__ __launch_bounds__(256) void wtrans4(
    const float* __restrict__ W0, const float* __restrict__ W1,
    const float* __restrict__ W2, const float* __restrict__ W3,
    ushort_t* __restrict__ Wt) {
  __shared__ unsigned tr[64][65];
  const int z = blockIdx.z;
  const float* W = (z == 0) ? W0 : (z == 1) ? W1 : (z == 2) ? W2 : W3;
  ushort_t* dst = Wt + (size_t)z * 1048576;
  const int k0 = blockIdx.y * 64, n0 = blockIdx.x * 64;
  const int tid = threadIdx.x;
  {
    const int rr = tid >> 4, c4 = tid & 15;
#pragma unroll
    for (int p = 0; p < 4; ++p) {
      const int k = p * 16 + rr;
      float4 v = *(const float4*)(W + (size_t)(k0 + k) * 1024 + n0 + c4 * 4);
      tr[c4*4+0][k] = f2bf(v.x); tr[c4*4+1][k] = f2bf(v.y);
      tr[c4*4+2][k] = f2bf(v.z); tr[c4*4+3][k] = f2bf(v.w);
    }
  }
  __syncthreads();
  const int r = tid >> 3, s = tid & 7;
#pragma unroll
  for (int p = 0; p < 2; ++p) {
    const int n = p * 32 + r;
    us8 o;
#pragma unroll
    for (int j = 0; j < 8; ++j) o[j] = (ushort_t)tr[n][s*8+j];
    *(us8*)(dst + (size_t)(n0 + n) * 1024 + k0 + s * 8) = o;
  }
}

// -------------------- per-head (2048x64) bf16 -> (64x2048) bf16 (V transpose)
__global__ __launch_bounds__(256) void vtrans(const ushort_t* __restrict__ Pv,
                                              ushort_t* __restrict__ Pvt) {
  __shared__ unsigned tr[64][65];
  const int t0 = blockIdx.x * 64, hd = blockIdx.y;
  const ushort_t* src = Pv + (size_t)hd * 131072;
  ushort_t* dst = Pvt + (size_t)hd * 131072;
  const int tid = threadIdx.x;
  const int r = tid >> 3, s = tid & 7;
#pragma unroll
  for (int p = 0; p < 2; ++p) {
    const int t = p * 32 + r;
    us8 v = *(const us8*)(src + (size_t)(t0 + t) * 64 + s * 8);
#pragma unroll
    for (int j = 0; j < 8; ++j) tr[s*8+j][t] = v[j];
  }
  __syncthreads();
#pragma unroll
  for (int p = 0; p < 2; ++p) {
    const int d = p * 32 + r;
    us8 o;
#pragma unroll
    for (int j = 0; j < 8; ++j) o[j] = (ushort_t)tr[d][s*8+j];
    *(us8*)(dst + (size_t)d * 2048 + t0 + s * 8) = o;
  }
}

// ----------------------------------------------------------------- bf16 GEMM
// C[M,N] = A[M,K] @ Bt[N,K]^T + bias. 128x128 tile, BK=64, 4 waves of 64x64.
// 2-phase prefetch: next tile's global_load_lds issued before current compute;
// counted s_waitcnt vmcnt(8) keeps them in flight across raw s_barrier.
template<int OUTF32>
__global__ __launch_bounds__(256) void gemm_bf16(
    const ushort_t* __restrict__ A, const ushort_t* __restrict__ Bt,
    const float* __restrict__ bias, void* __restrict__ Cout,
    int Mdim, int Ndim, int Kdim)
{
  __shared__ __align__(16) ushort_t As[2][128 * 64];
  __shared__ __align__(16) ushort_t Bs[2][128 * 64];
  const int tid = threadIdx.x;
  const int m0 = blockIdx.y * 128, n0 = blockIdx.x * 128;
  const int w = tid >> 6, lane = tid & 63, lo = lane & 15, hi = lane >> 4;
  const int wm = (w >> 1) * 64, wn = (w & 1) * 64;
  const int srow = tid >> 3, sslot = tid & 7;

  f4v acc[4][4];
#pragma unroll
  for (int i = 0; i < 4; ++i)
#pragma unroll
    for (int j = 0; j < 4; ++j) { f4v z = {0.f,0.f,0.f,0.f}; acc[i][j] = z; }

  const int NT = Kdim >> 6;   // 16

#define G_STAGE(buf, k0)                                                     \
  {                                                                          \
    _Pragma("unroll")                                                        \
    for (int i = 0; i < 4; ++i) {                                            \
      const int row = i * 32 + srow;                                         \
      const int sw = (sslot ^ (row & 7)) * 8;                                \
      gload16(A  + (size_t)(m0 + row) * Kdim + (k0) + sw,                    \
              &As[buf][(i * 256 + tid) * 8]);                                \
      gload16(Bt + (size_t)(n0 + row) * Kdim + (k0) + sw,                    \
              &Bs[buf][(i * 256 + tid) * 8]);                                \
    }                                                                        \
  }

  G_STAGE(0, 0);
  int cur = 0;
  for (int t = 0; t < NT; ++t) {
    if (t + 1 < NT) { G_STAGE(cur ^ 1, (t + 1) * 64); VMCNT(8); }
    else            { VMCNT(0); }
    BAR(); LFENCE();
    const ushort_t* Ab = &As[cur][0];
    const ushort_t* Bb = &Bs[cur][0];
#pragma unroll
    for (int ks = 0; ks < 2; ++ks) {
      const int slot = ks * 4 + hi;
      s8v av[4], bv[4];
#pragma unroll
      for (int i = 0; i < 4; ++i) {
        const int ra = wm + i * 16 + lo;
        av[i] = *(const s8v*)&Ab[ra * 64 + ((slot ^ (ra & 7)) << 3)];
        const int rb = wn + i * 16 + lo;
        bv[i] = *(const s8v*)&Bb[rb * 64 + ((slot ^ (rb & 7)) << 3)];
      }
#pragma unroll
      for (int am = 0; am < 4; ++am)
#pragma unroll
        for (int an = 0; an < 4; ++an)
          acc[am][an] = __builtin_amdgcn_mfma_f32_16x16x32_bf16(
              av[am], bv[an], acc[am][an], 0, 0, 0);
    }
    LFENCE(); BAR();
    cur ^= 1;
  }
#undef G_STAGE

#pragma unroll
  for (int an = 0; an < 4; ++an) {
    const int n = n0 + wn + an * 16 + lo;
    const float bsv = bias[n];
#pragma unroll
    for (int am = 0; am < 4; ++am) {
      const int mb = m0 + wm + am * 16 + hi * 4;
#pragma unroll
      for (int r = 0; r < 4; ++r) {
        const float v = acc[am][an][r] + bsv;
        if (OUTF32) ((float*)Cout)[(size_t)(mb + r) * Ndim + n] = v;
        else ((ushort_t*)Cout)[(size_t)(mb + r) * Ndim + n] = f2bf(v);
      }
    }
  }
}

// -------------------------------------------------------- fused causal attention
// 1D grid, qt = 31 - id/64 (longest blocks dispatch first), hd = id%64.
// Double-buffered K/V^T staging (counted vmcnt(4) across raw barriers),
// bf16 P buffer, deferred row-sum reduction, setprio around MFMA clusters.
__global__ __launch_bounds__(256) void attn_mfma(
    const ushort_t* __restrict__ Pq, const ushort_t* __restrict__ Pk,
    const ushort_t* __restrict__ Pvt, ushort_t* __restrict__ Ao)
{
  __shared__ __align__(16) ushort_t Ks[2][64 * 64];
  __shared__ __align__(16) ushort_t Vts[2][64 * 64];
  __shared__ __align__(16) ushort_t Psb[64 * 64];

  const int tid = threadIdx.x;
  const int id = blockIdx.x;
  const int qt = 31 - (id >> 6);
  const int hd = id & 63;
  const int b = hd >> 4, h = hd & 15;
  const int w = tid >> 6, lane = tid & 63, lo = lane & 15, hi = lane >> 4;
  const ushort_t* Qh = Pq + (size_t)hd * 131072;
  const ushort_t* Kh = Pk + (size_t)hd * 131072;
  const ushort_t* Vh = Pvt + (size_t)hd * 131072;
  const int srow = tid >> 3, sslot = tid & 7;

  s8v qa[2];
#pragma unroll
  for (int ks = 0; ks < 2; ++ks)
    qa[ks] = *(const s8v*)(Qh + (size_t)(qt * 64 + w * 16 + lo) * 64 + ks * 32 + hi * 8);

  f4v od[4];
#pragma unroll
  for (int f = 0; f < 4; ++f) { f4v z = {0.f,0.f,0.f,0.f}; od[f] = z; }
  float m[4], l[4];
#pragma unroll
  for (int r = 0; r < 4; ++r) { m[r] = -INFINITY; l[r] = 0.f; }

#define A_STAGE(buf, kt_)                                                    \
  {                                                                          \
    _Pragma("unroll")                                                        \
    for (int i = 0; i < 2; ++i) {                                            \
      const int row = i * 32 + srow;                                         \
      const int sw = (sslot ^ (row & 7)) * 8;                                \
      gload16(Kh + (size_t)((kt_) * 64 + row) * 64 + sw,                     \
              &Ks[buf][(i * 256 + tid) * 8]);                                \
      gload16(Vh + (size_t)row * 2048 + (kt_) * 64 + sw,                     \
              &Vts[buf][(i * 256 + tid) * 8]);                               \
    }                                                                        \
  }

  A_STAGE(0, 0);
  int cur = 0;
  for (int kt = 0; kt <= qt; ++kt) {
    if (kt < qt) { A_STAGE(cur ^ 1, kt + 1); VMCNT(4); }
    else         { VMCNT(0); }
    BAR(); LFENCE();
    const ushort_t* Kb = &Ks[cur][0];
    const ushort_t* Vb = &Vts[cur][0];

    // ---- S = Q K^T (C-layout: lane holds S[4hi+r][16f+lo]) ----
    f4v sf[4];
#pragma unroll
    for (int f = 0; f < 4; ++f) { f4v z = {0.f,0.f,0.f,0.f}; sf[f] = z; }
    __builtin_amdgcn_s_setprio(1);
#pragma unroll
    for (int ks = 0; ks < 2; ++ks) {
      const int slot = ks * 4 + hi;
      s8v kb[4];
#pragma unroll
      for (int f = 0; f < 4; ++f) {
        const int rk = f * 16 + lo;
        kb[f] = *(const s8v*)&Kb[rk * 64 + ((slot ^ (rk & 7)) << 3)];
      }
#pragma unroll
      for (int f = 0; f < 4; ++f)
        sf[f] = __builtin_amdgcn_mfma_f32_16x16x32_bf16(qa[ks], kb[f], sf[f], 0, 0, 0);
    }
    __builtin_amdgcn_s_setprio(0);

    // ---- online softmax (deferred row-sum: l stays per-lane partial) ----
    float sc[4][4];
#pragma unroll
    for (int f = 0; f < 4; ++f)
#pragma unroll
      for (int r = 0; r < 4; ++r) sc[r][f] = sf[f][r] * 0.03125f;
    if (kt == qt) {
#pragma unroll
      for (int r = 0; r < 4; ++r)
#pragma unroll
        for (int f = 0; f < 4; ++f)
          if (16 * f + lo > 16 * w + 4 * hi + r) sc[r][f] = -INFINITY;
    }
    float rmax[4];
#pragma unroll
    for (int r = 0; r < 4; ++r)
      rmax[r] = fmaxf(fmaxf(sc[r][0], sc[r][1]), fmaxf(sc[r][2], sc[r][3]));
#pragma unroll
    for (int x = 1; x < 16; x <<= 1)
#pragma unroll
      for (int r = 0; r < 4; ++r) rmax[r] = fmaxf(rmax[r], __shfl_xor(rmax[r], x, 64));
#pragma unroll
    for (int r = 0; r < 4; ++r) {
      const float mn = fmaxf(m[r], rmax[r]);
      const float al = __expf(m[r] - mn);
      m[r] = mn;
      float rs = 0.f;
#pragma unroll
      for (int f = 0; f < 4; ++f) {
        const float p = __expf(sc[r][f] - mn);
        sc[r][f] = p; rs += p;
      }
      l[r] = l[r] * al + rs;
#pragma unroll
      for (int f = 0; f < 4; ++f) od[f][r] *= al;
    }

    // ---- stage P as bf16 (wave-private rows, slot8^(t&7) swizzle) ----
#pragma unroll
    for (int r = 0; r < 4; ++r) {
      const int t = 16 * w + 4 * hi + r;
#pragma unroll
      for (int f = 0; f < 4; ++f) {
        const int s = 16 * f + lo;
        Psb[t * 64 + (((s >> 3) ^ (t & 7)) << 3) + (s & 7)] = f2bf(sc[r][f]);
      }
    }

    // ---- O += P V ----
    {
      const int t = 16 * w + lo;
      __builtin_amdgcn_s_setprio(1);
#pragma unroll
      for (int ks = 0; ks < 2; ++ks) {
        const int slot = ks * 4 + hi;
        s8v pa = *(const s8v*)&Psb[t * 64 + ((slot ^ (t & 7)) << 3)];
        s8v vb[4];
#pragma unroll
        for (int f = 0; f < 4; ++f) {
          const int rd = f * 16 + lo;
          vb[f] = *(const s8v*)&Vb[rd * 64 + ((slot ^ (rd & 7)) << 3)];
        }
#pragma unroll
        for (int f = 0; f < 4; ++f)
          od[f] = __builtin_amdgcn_mfma_f32_16x16x32_bf16(pa, vb[f], od[f], 0, 0, 0);
      }
      __builtin_amdgcn_s_setprio(0);
    }
    LFENCE(); BAR();
    cur ^= 1;
  }
#undef A_STAGE

  // ---- epilogue: reduce deferred l across the 16 col-lanes, normalize ----
#pragma unroll
  for (int x = 1; x < 16; x <<= 1)
#pragma unroll
    for (int r = 0; r < 4; ++r) l[r] += __shfl_xor(l[r], x, 64);
  float inv[4];
#pragma unroll
  for (int r = 0; r < 4; ++r) inv[r] = 1.0f / l[r];
#pragma unroll
  for (int f = 0; f < 4; ++f)
#pragma unroll
    for (int r = 0; r < 4; ++r) {
      const int t = qt * 64 + 16 * w + 4 * hi + r;
      const int d = 16 * f + lo;
      Ao[(size_t)(b * 2048 + t) * 1024 + h * 64 + d] = f2bf(od[f][r] * inv[r]);
    }
}

// ---------------------------------------------------------------------------
extern "C" void kernel_launch(void* const* d_in, const int* in_sizes, int n_in,
                              void* d_out, int out_size, void* d_ws, size_t ws_size,
                              hipStream_t stream) {
  const float* q  = (const float*)d_in[0];
  const float* k  = (const float*)d_in[1];
  const float* v  = (const float*)d_in[2];
  const float* Wq = (const float*)d_in[3];
  const float* bq = (const float*)d_in[4];
  const float* Wk = (const float*)d_in[5];
  const float* bk = (const float*)d_in[6];
  const float* Wv = (const float*)d_in[7];
  const float* bv = (const float*)d_in[8];
  const float* Wo = (const float*)d_in[9];
  const float* bo = (const float*)d_in[10];
  float* out = (float*)d_out;

  char* wsb = (char*)d_ws;
  ushort_t* qb  = (ushort_t*)(wsb + 0);          // 16 MB each (q,k,v bf16)
  ushort_t* kb  = (ushort_t*)(wsb + 16777216);
  ushort_t* Wqt = (ushort_t*)(wsb + 50331648);   // 2 MB each, contiguous x4
  ushort_t* Pq  = (ushort_t*)(wsb + 58720256);
  ushort_t* Pk  = (ushort_t*)(wsb + 75497472);
  ushort_t* Pv  = (ushort_t*)(wsb + 92274688);   // end = 109,051,904 B
  ushort_t* Wkt = Wqt + 1048576;
  ushort_t* Wvt = Wqt + 2097152;
  ushort_t* Wot = Wqt + 3145728;
  ushort_t* vb  = (ushort_t*)(wsb + 33554432);
  ushort_t* Pvt = qb;   // qb dead after Q-projection
  ushort_t* Ao  = kb;   // kb dead after K-projection

  castk3<<<dim3(4096, 3), 256, 0, stream>>>(q, k, v, qb);
  wtrans4<<<dim3(16, 16, 4), 256, 0, stream>>>(Wq, Wk, Wv, Wo, Wqt);

  gemm_bf16<0><<<dim3(8, 64), 256, 0, stream>>>(qb, Wqt, bq, Pq, 8192, 1024, 1024);
  gemm_bf16<0><<<dim3(8, 64), 256, 0, stream>>>(kb, Wkt, bk, Pk, 8192, 1024, 1024);
  gemm_bf16<0><<<dim3(8, 64), 256, 0, stream>>>(vb, Wvt, bv, Pv, 8192, 1024, 1024);

  vtrans<<<dim3(32, 64), 256, 0, stream>>>(Pv, Pvt);
  attn_mfma<<<2048, 256, 0, stream>>>(Pq, Pk, Pvt, Ao);

  gemm_bf16<1><<<dim3(8, 64), 256, 0, stream>>>(Ao, Wot, bo, out, 8192, 1024, 1024);
}

// Round 4
// 337.303 us; speedup vs baseline: 8.0306x; 1.0907x over previous
//
#include <hip/hip_runtime.h>
#include <hip/hip_bf16.h>
#include <math.h>

// B=4, T=2048, E=1024, H=16, D=64. All GEMMs are 8192x1024x1024.
// Head hd=b*16+h of any projection = contiguous (2048x64) row-major block at
// offset hd*131072 elems (raw-reshape equivalence, validated round 1).
// Pq is pre-scaled by log2(e)/32 so attention softmax runs in exp2 domain.

typedef unsigned short ushort_t;
typedef __attribute__((ext_vector_type(8))) short s8v;      // 8 bf16 = 4 VGPR
typedef __attribute__((ext_vector_type(8))) unsigned short us8;
typedef __attribute__((ext_vector_type(4))) float f4v;

#define BAR()    __builtin_amdgcn_s_barrier()
#define LFENCE() asm volatile("" ::: "memory")
#define VMCNT(n) asm volatile("s_waitcnt vmcnt(" #n ")" ::: "memory")

__device__ __forceinline__ unsigned short f2bf(float x) {
  __hip_bfloat16 h = __float2bfloat16(x);
  unsigned short u; __builtin_memcpy(&u, &h, 2); return u;
}

__device__ __forceinline__ float exp2a(float x) {
  return __builtin_amdgcn_exp2f(x);   // bare v_exp_f32 (2^x)
}

__device__ __forceinline__ void gload16(const void* g, void* l) {
  __builtin_amdgcn_global_load_lds(
      (const __attribute__((address_space(1))) unsigned int*)g,
      (__attribute__((address_space(3))) unsigned int*)l, 16, 0, 0);
}

// -------------------------------------------- cast f32->bf16 (q,k,v in one)
__global__ __launch_bounds__(256) void castk3(const float* __restrict__ q,
                                              const float* __restrict__ k,
                                              const float* __restrict__ v,
                                              ushort_t* __restrict__ dst) {
  const int y = blockIdx.y;
  const float* src = (y == 0) ? q : (y == 1) ? k : v;
  ushort_t* d = dst + (size_t)y * 8388608;
  int i = blockIdx.x * 256 + threadIdx.x;   // 0..1048575 (x8 elems)
  const float4* s4 = (const float4*)src + (size_t)i * 2;
  float4 a = s4[0], b = s4[1];
  us8 o;
  o[0]=f2bf(a.x); o[1]=f2bf(a.y); o[2]=f2bf(a.z); o[3]=f2bf(a.w);
  o[4]=f2bf(b.x); o[5]=f2bf(b.y); o[6]=f2bf(b.z); o[7]=f2bf(b.w);
  *(us8*)(d + (size_t)i * 8) = o;
}

// ---------------------------- W (1024x1024 f32) -> W^T (N,K) bf16, 4 weights
__global__ __launch_bounds__(256) void wtrans4(
    const float* __restrict__ W0, const float* __restrict__ W1,
    const float* __restrict__ W2, const float* __restrict__ W3,
    ushort_t* __restrict__ Wt) {
  __shared__ unsigned tr[64][65];
  const int z = blockIdx.z;
  const float* W = (z == 0) ? W0 : (z == 1) ? W1 : (z == 2) ? W2 : W3;
  ushort_t* dst = Wt + (size_t)z * 1048576;
  const int k0 = blockIdx.y * 64, n0 = blockIdx.x * 64;
  const int tid = threadIdx.x;
  {
    const int rr = tid >> 4, c4 = tid & 15;
#pragma unroll
    for (int p = 0; p < 4; ++p) {
      const int k = p * 16 + rr;
      float4 v = *(const float4*)(W + (size_t)(k0 + k) * 1024 + n0 + c4 * 4);
      tr[c4*4+0][k] = f2bf(v.x); tr[c4*4+1][k] = f2bf(v.y);
      tr[c4*4+2][k] = f2bf(v.z); tr[c4*4+3][k] = f2bf(v.w);
    }
  }
  __syncthreads();
  const int r = tid >> 3, s = tid & 7;
#pragma unroll
  for (int p = 0; p < 2; ++p) {
    const int n = p * 32 + r;
    us8 o;
#pragma unroll
    for (int j = 0; j < 8; ++j) o[j] = (ushort_t)tr[n][s*8+j];
    *(us8*)(dst + (size_t)(n0 + n) * 1024 + k0 + s * 8) = o;
  }
}

// -------------------- per-head (2048x64) bf16 -> (64x2048) bf16 (V transpose)
__global__ __launch_bounds__(256) void vtrans(const ushort_t* __restrict__ Pv,
                                              ushort_t* __restrict__ Pvt) {
  __shared__ unsigned tr[64][65];
  const int t0 = blockIdx.x * 64, hd = blockIdx.y;
  const ushort_t* src = Pv + (size_t)hd * 131072;
  ushort_t* dst = Pvt + (size_t)hd * 131072;
  const int tid = threadIdx.x;
  const int r = tid >> 3, s = tid & 7;
#pragma unroll
  for (int p = 0; p < 2; ++p) {
    const int t = p * 32 + r;
    us8 v = *(const us8*)(src + (size_t)(t0 + t) * 64 + s * 8);
#pragma unroll
    for (int j = 0; j < 8; ++j) tr[s*8+j][t] = v[j];
  }
  __syncthreads();
#pragma unroll
  for (int p = 0; p < 2; ++p) {
    const int d = p * 32 + r;
    us8 o;
#pragma unroll
    for (int j = 0; j < 8; ++j) o[j] = (ushort_t)tr[d][s*8+j];
    *(us8*)(dst + (size_t)d * 2048 + t0 + s * 8) = o;
  }
}

// ----------------------------------------------------------------- bf16 GEMM
// C[M,N] = A[M,K] @ Bt[N,K]^T + bias, scaled. 128x128 tile, BK=64, 4 waves of
// 64x64. Compile-time 2-step double-buffer: stage next tile via global_load_lds
// (inverse-swizzled source, linear dest), counted vmcnt(8) across raw barriers.
template<int OUTF32>
__device__ __forceinline__ void gemm_body(
    ushort_t* As, ushort_t* Bs,   // LDS, [2][8192] each, flat
    const ushort_t* __restrict__ A, const ushort_t* __restrict__ Bt,
    const float* __restrict__ bias, void* __restrict__ Cout,
    float scale, int m0, int n0)
{
  const int tid = threadIdx.x;
  const int w = tid >> 6, lane = tid & 63, lo = lane & 15, hi = lane >> 4;
  const int wm = (w >> 1) * 64, wn = (w & 1) * 64;
  const int srow = tid >> 3, sslot = tid & 7;

  f4v acc[4][4];
#pragma unroll
  for (int i = 0; i < 4; ++i)
#pragma unroll
    for (int j = 0; j < 4; ++j) { f4v z = {0.f,0.f,0.f,0.f}; acc[i][j] = z; }

  auto stage = [&](int buf, int kt) {
    ushort_t* Ad = &As[buf * 8192];
    ushort_t* Bd = &Bs[buf * 8192];
#pragma unroll
    for (int i = 0; i < 4; ++i) {
      const int row = i * 32 + srow;
      const int sw = (sslot ^ (row & 7)) * 8;
      gload16(A  + (size_t)(m0 + row) * 1024 + kt * 64 + sw, &Ad[(i * 256 + tid) * 8]);
      gload16(Bt + (size_t)(n0 + row) * 1024 + kt * 64 + sw, &Bd[(i * 256 + tid) * 8]);
    }
  };

  auto compute = [&](const ushort_t* Ab, const ushort_t* Bb) {
#pragma unroll
    for (int ks = 0; ks < 2; ++ks) {
      const int slot = ks * 4 + hi;
      s8v av[4], bv[4];
#pragma unroll
      for (int i = 0; i < 4; ++i) {
        const int ra = wm + i * 16 + lo;
        av[i] = *(const s8v*)&Ab[ra * 64 + ((slot ^ (ra & 7)) << 3)];
        const int rb = wn + i * 16 + lo;
        bv[i] = *(const s8v*)&Bb[rb * 64 + ((slot ^ (rb & 7)) << 3)];
      }
#pragma unroll
      for (int am = 0; am < 4; ++am)
#pragma unroll
        for (int an = 0; an < 4; ++an)
          acc[am][an] = __builtin_amdgcn_mfma_f32_16x16x32_bf16(
              av[am], bv[an], acc[am][an], 0, 0, 0);
    }
  };

  stage(0, 0);
  for (int t = 0; t < 16; t += 2) {
    stage(1, t + 1); VMCNT(8);
    BAR(); LFENCE();
    compute(&As[0], &Bs[0]);
    LFENCE(); BAR();
    if (t + 2 < 16) { stage(0, t + 2); VMCNT(8); }
    else            { VMCNT(0); }
    BAR(); LFENCE();
    compute(&As[8192], &Bs[8192]);
    LFENCE(); BAR();
  }

#pragma unroll
  for (int an = 0; an < 4; ++an) {
    const int n = n0 + wn + an * 16 + lo;
    const float bsv = bias[n];
#pragma unroll
    for (int am = 0; am < 4; ++am) {
      const int mb = m0 + wm + am * 16 + hi * 4;
#pragma unroll
      for (int r = 0; r < 4; ++r) {
        const float v = (acc[am][an][r] + bsv) * scale;
        if (OUTF32) ((float*)Cout)[(size_t)(mb + r) * 1024 + n] = v;
        else ((ushort_t*)Cout)[(size_t)(mb + r) * 1024 + n] = f2bf(v);
      }
    }
  }
}

// Batched Q/K/V projection: z selects input/weight/bias/output; Q pre-scaled
// by log2(e)/32 so attention runs exp2-domain softmax.
__global__ __launch_bounds__(256) void gemm_qkv(
    const ushort_t* __restrict__ Abase, const ushort_t* __restrict__ Wbase,
    const float* __restrict__ bq, const float* __restrict__ bk,
    const float* __restrict__ bv, ushort_t* __restrict__ Cbase)
{
  __shared__ __align__(16) ushort_t As[2 * 8192];
  __shared__ __align__(16) ushort_t Bs[2 * 8192];
  const int z = blockIdx.z;
  const ushort_t* A  = Abase + (size_t)z * 8388608;
  const ushort_t* Bt = Wbase + (size_t)z * 1048576;
  const float* bias = (z == 0) ? bq : (z == 1) ? bk : bv;
  const float scale = (z == 0) ? 0.04508422002778011f : 1.0f;  // log2(e)/32
  gemm_body<0>(As, Bs, A, Bt, bias, Cbase + (size_t)z * 8388608,
               scale, blockIdx.y * 128, blockIdx.x * 128);
}

__global__ __launch_bounds__(256) void gemm_out(
    const ushort_t* __restrict__ A, const ushort_t* __restrict__ Bt,
    const float* __restrict__ bias, float* __restrict__ Cout)
{
  __shared__ __align__(16) ushort_t As[2 * 8192];
  __shared__ __align__(16) ushort_t Bs[2 * 8192];
  gemm_body<1>(As, Bs, A, Bt, bias, Cout, 1.0f,
               blockIdx.y * 128, blockIdx.x * 128);
}

// -------------------------------------------------------- fused causal attention
// 8 waves, 128-row Q tile, 64-key K/V tiles, exp2-domain online softmax with
// defer-max (skip shfl reduce + rescale when tile max within m+8). Double-
// buffered K/V^T staging via counted vmcnt(2), compile-time 2-step unroll
// (tile count NT = 2qt+2 is always even). Psb rows are wave-private.
__global__ __launch_bounds__(512) void attn_mfma(
    const ushort_t* __restrict__ Pq, const ushort_t* __restrict__ Pk,
    const ushort_t* __restrict__ Pvt, ushort_t* __restrict__ Ao)
{
  __shared__ __align__(16) ushort_t Ks[2 * 4096];
  __shared__ __align__(16) ushort_t Vts[2 * 4096];
  __shared__ __align__(16) ushort_t Psb[128 * 64];

  const int tid = threadIdx.x;
  const int id = blockIdx.x;
  const int qt = 15 - (id >> 6);    // longest blocks dispatch first
  const int hd = id & 63;
  const int b = hd >> 4, h = hd & 15;
  const int w = tid >> 6, lane = tid & 63, lo = lane & 15, hi = lane >> 4;
  const ushort_t* Qh = Pq + (size_t)hd * 131072;
  const ushort_t* Kh = Pk + (size_t)hd * 131072;
  const ushort_t* Vh = Pvt + (size_t)hd * 131072;
  const int srow = tid >> 3, sslot = tid & 7;   // 512 threads -> srow 0..63
  const int qt2 = 2 * qt;

  s8v qa[2];
#pragma unroll
  for (int ks = 0; ks < 2; ++ks)
    qa[ks] = *(const s8v*)(Qh + (size_t)(qt * 128 + w * 16 + lo) * 64 + ks * 32 + hi * 8);

  f4v od[4];
#pragma unroll
  for (int f = 0; f < 4; ++f) { f4v z = {0.f,0.f,0.f,0.f}; od[f] = z; }
  float m[4], l[4];
  int tg[4];
#pragma unroll
  for (int r = 0; r < 4; ++r) {
    m[r] = -INFINITY; l[r] = 0.f;
    tg[r] = qt * 128 + 16 * w + 4 * hi + r;   // global q row
  }

  auto astage = [&](int buf, int kt) {
    const int sw = (sslot ^ (srow & 7)) * 8;
    gload16(Kh + (size_t)(kt * 64 + srow) * 64 + sw, &Ks[buf * 4096 + tid * 8]);
    gload16(Vh + (size_t)srow * 2048 + kt * 64 + sw, &Vts[buf * 4096 + tid * 8]);
  };

  auto acompute = [&](const ushort_t* Kb, const ushort_t* Vb, int kt_) {
    // ---- S = Q K^T (exp2 domain; C-layout: lane holds S[4hi+r][16f+lo]) ----
    f4v sf[4];
#pragma unroll
    for (int f = 0; f < 4; ++f) { f4v z = {0.f,0.f,0.f,0.f}; sf[f] = z; }
    __builtin_amdgcn_s_setprio(1);
#pragma unroll
    for (int ks = 0; ks < 2; ++ks) {
      const int slot = ks * 4 + hi;
      s8v kb[4];
#pragma unroll
      for (int f = 0; f < 4; ++f) {
        const int rk = f * 16 + lo;
        kb[f] = *(const s8v*)&Kb[rk * 64 + ((slot ^ (rk & 7)) << 3)];
      }
#pragma unroll
      for (int f = 0; f < 4; ++f)
        sf[f] = __builtin_amdgcn_mfma_f32_16x16x32_bf16(qa[ks], kb[f], sf[f], 0, 0, 0);
    }
    __builtin_amdgcn_s_setprio(0);

    float sc[4][4];
#pragma unroll
    for (int f = 0; f < 4; ++f)
#pragma unroll
      for (int r = 0; r < 4; ++r) sc[r][f] = sf[f][r];
    if (kt_ >= qt2) {   // only the two diagonal-adjacent tiles need masking
#pragma unroll
      for (int r = 0; r < 4; ++r)
#pragma unroll
        for (int f = 0; f < 4; ++f)
          if (kt_ * 64 + 16 * f + lo > tg[r]) sc[r][f] = -INFINITY;
    }

    // ---- defer-max online softmax ----
    float lmax[4];
#pragma unroll
    for (int r = 0; r < 4; ++r)
      lmax[r] = fmaxf(fmaxf(sc[r][0], sc[r][1]), fmaxf(sc[r][2], sc[r][3]));
    const int ok = (lmax[0] <= m[0] + 8.f) & (lmax[1] <= m[1] + 8.f) &
                   (lmax[2] <= m[2] + 8.f) & (lmax[3] <= m[3] + 8.f);
    if (!__all(ok)) {   // full reduce + rescale (rare after warm-up)
      float rmax[4];
#pragma unroll
      for (int r = 0; r < 4; ++r) rmax[r] = lmax[r];
#pragma unroll
      for (int x = 1; x < 16; x <<= 1)
#pragma unroll
        for (int r = 0; r < 4; ++r)
          rmax[r] = fmaxf(rmax[r], __shfl_xor(rmax[r], x, 64));
#pragma unroll
      for (int r = 0; r < 4; ++r) {
        const float mn = fmaxf(m[r], rmax[r]);
        const float al = exp2a(m[r] - mn);   // exp2(-inf)=0 on first tile
        m[r] = mn; l[r] *= al;
#pragma unroll
        for (int f = 0; f < 4; ++f) od[f][r] *= al;
      }
    }
#pragma unroll
    for (int r = 0; r < 4; ++r) {
      float rs = 0.f;
#pragma unroll
      for (int f = 0; f < 4; ++f) {
        const float p = exp2a(sc[r][f] - m[r]);   // bounded by 2^8
        sc[r][f] = p; rs += p;
      }
      l[r] += rs;   // per-lane partial; cross-lane reduce deferred to epilogue
    }

    // ---- stage P as bf16 (wave-private rows, slot8^(t&7) swizzle) ----
#pragma unroll
    for (int r = 0; r < 4; ++r) {
      const int t = 16 * w + 4 * hi + r;
#pragma unroll
      for (int f = 0; f < 4; ++f) {
        const int s = 16 * f + lo;
        Psb[t * 64 + (((s >> 3) ^ (t & 7)) << 3) + (s & 7)] = f2bf(sc[r][f]);
      }
    }

    // ---- O += P V ----
    {
      const int t = 16 * w + lo;
      __builtin_amdgcn_s_setprio(1);
#pragma unroll
      for (int ks = 0; ks < 2; ++ks) {
        const int slot = ks * 4 + hi;
        s8v pa = *(const s8v*)&Psb[t * 64 + ((slot ^ (t & 7)) << 3)];
        s8v vb[4];
#pragma unroll
        for (int f = 0; f < 4; ++f) {
          const int rd = f * 16 + lo;
          vb[f] = *(const s8v*)&Vb[rd * 64 + ((slot ^ (rd & 7)) << 3)];
        }
#pragma unroll
        for (int f = 0; f < 4; ++f)
          od[f] = __builtin_amdgcn_mfma_f32_16x16x32_bf16(pa, vb[f], od[f], 0, 0, 0);
      }
      __builtin_amdgcn_s_setprio(0);
    }
  };

  const int NT = qt2 + 2;   // always even
  astage(0, 0);
  for (int t2 = 0; t2 < NT; t2 += 2) {
    astage(1, t2 + 1); VMCNT(2);
    BAR(); LFENCE();
    acompute(&Ks[0], &Vts[0], t2);
    LFENCE(); BAR();
    if (t2 + 2 < NT) { astage(0, t2 + 2); VMCNT(2); }
    else             { VMCNT(0); }
    BAR(); LFENCE();
    acompute(&Ks[4096], &Vts[4096], t2 + 1);
    LFENCE(); BAR();
  }

  // ---- epilogue: reduce deferred l across the 16 col-lanes, normalize ----
#pragma unroll
  for (int x = 1; x < 16; x <<= 1)
#pragma unroll
    for (int r = 0; r < 4; ++r) l[r] += __shfl_xor(l[r], x, 64);
  float inv[4];
#pragma unroll
  for (int r = 0; r < 4; ++r) inv[r] = 1.0f / l[r];
#pragma unroll
  for (int f = 0; f < 4; ++f)
#pragma unroll
    for (int r = 0; r < 4; ++r) {
      const int d = 16 * f + lo;
      Ao[(size_t)(b * 2048 + tg[r]) * 1024 + h * 64 + d] = f2bf(od[f][r] * inv[r]);
    }
}

// ---------------------------------------------------------------------------
extern "C" void kernel_launch(void* const* d_in, const int* in_sizes, int n_in,
                              void* d_out, int out_size, void* d_ws, size_t ws_size,
                              hipStream_t stream) {
  const float* q  = (const float*)d_in[0];
  const float* k  = (const float*)d_in[1];
  const float* v  = (const float*)d_in[2];
  const float* Wq = (const float*)d_in[3];
  const float* bq = (const float*)d_in[4];
  const float* Wk = (const float*)d_in[5];
  const float* bk = (const float*)d_in[6];
  const float* Wv = (const float*)d_in[7];
  const float* bv = (const float*)d_in[8];
  const float* Wo = (const float*)d_in[9];
  const float* bo = (const float*)d_in[10];
  float* out = (float*)d_out;

  char* wsb = (char*)d_ws;
  ushort_t* qb  = (ushort_t*)(wsb + 0);          // 16 MB each (q,k,v bf16)
  ushort_t* Wqt = (ushort_t*)(wsb + 50331648);   // 2 MB each, contiguous x4
  ushort_t* Pq  = (ushort_t*)(wsb + 58720256);   // 16 MB each, contiguous x3
  ushort_t* kbb = (ushort_t*)(wsb + 16777216);
  ushort_t* Pv  = (ushort_t*)(wsb + 92274688);   // end = 109,051,904 B
  ushort_t* Wot = Wqt + 3145728;
  ushort_t* Pvt = qb;    // qb dead after projections
  ushort_t* Ao  = kbb;   // kb dead after projections

  castk3<<<dim3(4096, 3), 256, 0, stream>>>(q, k, v, qb);
  wtrans4<<<dim3(16, 16, 4), 256, 0, stream>>>(Wq, Wk, Wv, Wo, Wqt);

  gemm_qkv<<<dim3(8, 64, 3), 256, 0, stream>>>(qb, Wqt, bq, bk, bv, Pq);

  vtrans<<<dim3(32, 64), 256, 0, stream>>>(Pv, Pvt);
  attn_mfma<<<1024, 512, 0, stream>>>(Pq, Pq + 8388608, Pvt, Ao);

  gemm_out<<<dim3(8, 64), 256, 0, stream>>>(Ao, Wot, bo, out);
}